// Round 5
// baseline (170.938 us; speedup 1.0000x reference)
//
#include <hip/hip_runtime.h>
#include <hip/hip_bf16.h>

// LIF: V = V + (I - V)/tau; spike = V >= 1.0; V = spike ? 0 : V
// d_out = [spike_trace (0/1 f32) | voltage_trace (f32)], each T*B*N.
//
// Memory-bound streaming: 268 MB read + 537 MB write, zero reuse.
// R4: software-pipelined register double-buffer (A/B batches, named — no
// runtime-indexed array, rule #20). Loads for batch k+1 are issued BEFORE
// the stores of batch k, so the s_waitcnt vmcnt(N) that gates load
// consumption no longer forces the previous batch's 16 stores to drain
// (vmcnt counts loads+stores in issue order — m135). Scalar dword access
// keeps max TLP: 131072 threads = 2048 waves = 2 waves/SIMD (float4 cut
// waves 4x and regressed, R3).

#define LIF_T 512
#define V_TH 1.0f
#define TAU 20.0f
#define U 8
#define NB (LIF_T / U)   // 64 batches

__global__ __launch_bounds__(256) void lif_kernel(const float* __restrict__ in,
                                                  float* __restrict__ spikes,
                                                  float* __restrict__ volts,
                                                  int BN) {
    const int i = blockIdx.x * blockDim.x + threadIdx.x;
    if (i >= BN) return;

    const size_t stride = (size_t)BN;
    const size_t base = (size_t)i;

    float A[U], B[U];
    float V = 0.0f;

    // Prologue: load batch 0 into A.
    #pragma unroll
    for (int u = 0; u < U; ++u)
        A[u] = __builtin_nontemporal_load(&in[base + (size_t)u * stride]);

    #pragma unroll 1
    for (int b = 0; b < NB; b += 2) {
        // Issue loads for batch b+1 BEFORE storing batch b.
        {
            const size_t offB = base + (size_t)((b + 1) * U) * stride;
            #pragma unroll
            for (int u = 0; u < U; ++u)
                B[u] = __builtin_nontemporal_load(&in[offB + (size_t)u * stride]);
        }
        // Compute + store batch b from A.
        {
            const size_t o0 = base + (size_t)(b * U) * stride;
            #pragma unroll
            for (int u = 0; u < U; ++u) {
                const size_t o = o0 + (size_t)u * stride;
                // EXACT reference op order: sub, IEEE div by 20.0f, add.
                V = V + (A[u] - V) / TAU;
                const bool s = (V >= V_TH);
                __builtin_nontemporal_store(s ? 1.0f : 0.0f, &spikes[o]);
                V = s ? 0.0f : V;
                __builtin_nontemporal_store(V, &volts[o]);
            }
        }
        // Issue loads for batch b+2 into A (tail: clamp -> harmless re-read).
        {
            const int nb2 = (b + 2 < NB) ? (b + 2) : (NB - 1);
            const size_t offA = base + (size_t)(nb2 * U) * stride;
            #pragma unroll
            for (int u = 0; u < U; ++u)
                A[u] = __builtin_nontemporal_load(&in[offA + (size_t)u * stride]);
        }
        // Compute + store batch b+1 from B.
        {
            const size_t o0 = base + (size_t)((b + 1) * U) * stride;
            #pragma unroll
            for (int u = 0; u < U; ++u) {
                const size_t o = o0 + (size_t)u * stride;
                V = V + (B[u] - V) / TAU;
                const bool s = (V >= V_TH);
                __builtin_nontemporal_store(s ? 1.0f : 0.0f, &spikes[o]);
                V = s ? 0.0f : V;
                __builtin_nontemporal_store(V, &volts[o]);
            }
        }
    }
}

extern "C" void kernel_launch(void* const* d_in, const int* in_sizes, int n_in,
                              void* d_out, int out_size, void* d_ws, size_t ws_size,
                              hipStream_t stream) {
    const float* in = (const float*)d_in[0];
    float* out = (float*)d_out;

    const int total = in_sizes[0];          // T*B*N
    const int BN = total / LIF_T;           // 131072

    float* spikes = out;                     // first T*B*N floats
    float* volts  = out + (size_t)total;     // second T*B*N floats

    const int block = 256;
    const int grid = (BN + block - 1) / block;   // 512 blocks = 2/CU, 8 waves/CU
    lif_kernel<<<grid, block, 0, stream>>>(in, spikes, volts, BN);
}